// Round 3
// baseline (18148.262 us; speedup 1.0000x reference)
//
#include <hip/hip_runtime.h>

#define B_SZ   256
#define D_IN   512
#define T_LEN  512
#define H_DIM  1024
#define KTOT   1536   // H_DIM + D_IN
#define NCLASS 1000
#define NBLK   256

using half8   = __attribute__((ext_vector_type(8))) _Float16;
using floatx4 = __attribute__((ext_vector_type(4))) float;

__device__ __forceinline__ float ftanh(float x) {
    x = fminf(fmaxf(x, -20.f), 20.f);
    float e = __expf(2.f * x);
    return (e - 1.f) / (e + 1.f);
}

// ---------------------------------------------------------------------------
// Transpose x [B][D][T] fp32 -> xT [T][B][D] f16
// ---------------------------------------------------------------------------
__global__ void k_transpose_x(const float* __restrict__ x, _Float16* __restrict__ xT) {
    __shared__ float tile[32][33];
    int b = blockIdx.z, d0 = blockIdx.y * 32, t0 = blockIdx.x * 32;
    int tx = threadIdx.x, ty = threadIdx.y;   // 32 x 8
    const float* xp = x + ((size_t)b * D_IN + d0) * T_LEN + t0;
#pragma unroll
    for (int i = 0; i < 4; ++i)
        tile[ty + i * 8][tx] = xp[(size_t)(ty + i * 8) * T_LEN + tx];
    __syncthreads();
#pragma unroll
    for (int i = 0; i < 4; ++i) {
        int t = t0 + ty + i * 8;
        xT[((size_t)t * B_SZ + b) * D_IN + d0 + tx] = (_Float16)tile[tx][ty + i * 8];
    }
}

// ---------------------------------------------------------------------------
// Build WcatT [4096][1536] f16 (column-major weights WcatT[n][k]).
// n = gate*1024 + j, gates in order g,f,i,o. k<1024 -> Wh[k][j], else Wx.
// ---------------------------------------------------------------------------
__global__ void k_build_wcat(const float* __restrict__ Wgh, const float* __restrict__ Wfh,
                             const float* __restrict__ Wih, const float* __restrict__ Woh,
                             const float* __restrict__ Wgx, const float* __restrict__ Wfx,
                             const float* __restrict__ Wix, const float* __restrict__ Wox,
                             _Float16* __restrict__ WcatT) {
    int src = blockIdx.z;
    int kmax = (src < 4) ? 1024 : 512;
    int koff = (src < 4) ? 0 : 1024;
    int gi = src & 3;
    const float* W;
    switch (src) {
        case 0: W = Wgh; break; case 1: W = Wfh; break;
        case 2: W = Wih; break; case 3: W = Woh; break;
        case 4: W = Wgx; break; case 5: W = Wfx; break;
        case 6: W = Wix; break; default: W = Wox; break;
    }
    int k0 = blockIdx.y * 32;
    if (k0 >= kmax) return;
    int j0 = blockIdx.x * 32;
    __shared__ float tile[32][33];
    int tx = threadIdx.x, ty = threadIdx.y;
#pragma unroll
    for (int i = 0; i < 4; ++i)
        tile[ty + i * 8][tx] = W[(size_t)(k0 + ty + i * 8) * 1024 + j0 + tx];
    __syncthreads();
#pragma unroll
    for (int i = 0; i < 4; ++i) {
        int n = gi * 1024 + j0 + ty + i * 8;
        WcatT[(size_t)n * KTOT + koff + k0 + tx] = (_Float16)tile[tx][ty + i * 8];
    }
}

// ---------------------------------------------------------------------------
// Init: zero h buffer 0, build bias[4096], zero grid barrier.
// ---------------------------------------------------------------------------
__global__ void k_init(unsigned int* __restrict__ h0u, float* __restrict__ bias,
                       unsigned int* __restrict__ bar,
                       const float* __restrict__ bg, const float* __restrict__ bf,
                       const float* __restrict__ bi, const float* __restrict__ bo) {
    int idx = blockIdx.x * 256 + threadIdx.x;       // grid 512 -> 131072
    if (idx < 131072) h0u[idx] = 0u;                // 262144 halves
    if (idx < 4096) {
        int gi = idx >> 10, j = idx & 1023;
        float v = (gi == 0) ? bg[j] : (gi == 1) ? bf[j] : (gi == 2) ? bi[j] : bo[j];
        bias[idx] = v;
    }
    if (idx == 0) *bar = 0u;
}

// ---------------------------------------------------------------------------
// Persistent LSTM: 256 WGs (1/CU) x 256 threads, cooperative launch.
// WG owns 64 batch rows x 16 h-cols (x4 gates). Wh slice LDS-resident.
// Wave (wm,wn): rows [wm*32, wm*32+32), gates {2wn, 2wn+1}. c in registers.
// ---------------------------------------------------------------------------
__global__ __launch_bounds__(256, 1)
void k_lstm(const _Float16* __restrict__ xT, const _Float16* __restrict__ WcatT,
            const float* __restrict__ bias, _Float16* __restrict__ hb0,
            _Float16* __restrict__ hb1, float* __restrict__ hf32,
            unsigned int* __restrict__ bar) {
    __shared__ __align__(16) _Float16 Ws[64][1032];  // 132 KB (pad 8 -> 4-bank row shift)
    __shared__ float Ex[4][64][17];                  // 17 KB gate-exchange
    __shared__ float biasS[4][16];

    const int bid = blockIdx.x;
    const int xcd = bid & 7, loc = bid >> 3;
    const int cg  = xcd * 8 + (loc & 7);   // [0,64) col group -> XCD-local L2 reuse
    const int bgp = loc >> 3;              // [0,4)  batch group
    const int r0 = bgp * 64, hc0 = cg * 16;
    const int tid = threadIdx.x, wave = tid >> 6, lane = tid & 63;
    const int wm = wave & 1, wn = wave >> 1;
    const int lm = lane & 15, lk = (lane >> 4) * 8;

    // ---- load Wh slice (64 rows x 1024 k) into LDS, once ----
#pragma unroll
    for (int it = 0; it < 32; ++it) {
        int u = it * 256 + tid;
        int n = u >> 7, kp = (u & 127) * 8;
        const _Float16* src = WcatT + (size_t)((n >> 4) * 1024 + hc0 + (n & 15)) * KTOT + kp;
        *(uint4*)&Ws[n][kp] = *(const uint4*)src;
    }
    if (tid < 64) biasS[tid >> 4][tid & 15] = bias[(tid >> 4) * 1024 + hc0 + (tid & 15)];
    __syncthreads();

    // epilogue cell ownership: row = tid>>2 (0..63), cols ec4..ec4+3
    const int erow = tid >> 2, ec4 = (tid & 3) * 4;
    float cst[4] = {0.f, 0.f, 0.f, 0.f};

    const int arow0 = r0 + wm * 32 + lm;         // global A row, mt adds 16
    const int nrow0 = wn * 32 + lm;              // Ws row, nt adds 16
    const int gate0 = 2 * wn;
    const _Float16* wxb[2] = {
        WcatT + (size_t)(gate0 * 1024 + hc0 + lm) * KTOT + 1024,
        WcatT + (size_t)((gate0 + 1) * 1024 + hc0 + lm) * KTOT + 1024
    };

    for (int t = 0; t < T_LEN; ++t) {
        const _Float16* h_in  = (t & 1) ? hb1 : hb0;
        _Float16*       h_out = (t & 1) ? hb0 : hb1;
        const _Float16* xr = xT + (size_t)t * (B_SZ * D_IN);

        floatx4 acc[2][2];
#pragma unroll
        for (int mt = 0; mt < 2; ++mt)
#pragma unroll
            for (int nt = 0; nt < 2; ++nt)
                acc[mt][nt] = (floatx4){0.f, 0.f, 0.f, 0.f};

        auto loadA = [&](int b, int kk, int mt) -> half8 {
            int koff = b * 128 + kk * 32 + lk;
            if (b < 8)
                return *(const half8*)(h_in + (size_t)(arow0 + mt * 16) * H_DIM + koff);
            else
                return *(const half8*)(xr + (size_t)(arow0 + mt * 16) * D_IN + (koff - 1024));
        };
        auto loadB = [&](int b, int kk, int nt) -> half8 {
            int koff = b * 128 + kk * 32 + lk;
            if (b < 8)
                return *(const half8*)&Ws[nrow0 + nt * 16][koff];
            else
                return *(const half8*)(wxb[nt] + (koff - 1024));
        };

        half8 Af[2][2][4], Bf[2][2][4];   // [buf][mt|nt][kk]
#pragma unroll
        for (int mt = 0; mt < 2; ++mt)
#pragma unroll
            for (int kk = 0; kk < 4; ++kk) {
                Af[0][mt][kk] = loadA(0, kk, mt);
                Bf[0][mt][kk] = loadB(0, kk, mt);
            }
#pragma unroll
        for (int b = 0; b < 12; ++b) {
            const int cur = b & 1, nxt = cur ^ 1;
            if (b < 11) {
#pragma unroll
                for (int mt = 0; mt < 2; ++mt)
#pragma unroll
                    for (int kk = 0; kk < 4; ++kk) {
                        Af[nxt][mt][kk] = loadA(b + 1, kk, mt);
                        Bf[nxt][mt][kk] = loadB(b + 1, kk, mt);
                    }
            }
#pragma unroll
            for (int kk = 0; kk < 4; ++kk)
#pragma unroll
                for (int mt = 0; mt < 2; ++mt)
#pragma unroll
                    for (int nt = 0; nt < 2; ++nt)
                        acc[mt][nt] = __builtin_amdgcn_mfma_f32_16x16x32_f16(
                            Af[cur][mt][kk], Bf[cur][nt][kk], acc[mt][nt], 0, 0, 0);
        }

        // ---- gate exchange: C/D layout col=lane&15, row=(lane>>4)*4+r ----
#pragma unroll
        for (int mt = 0; mt < 2; ++mt)
#pragma unroll
            for (int nt = 0; nt < 2; ++nt)
#pragma unroll
                for (int r = 0; r < 4; ++r)
                    Ex[gate0 + nt][wm * 32 + mt * 16 + (lane >> 4) * 4 + r][lm] = acc[mt][nt][r];
        __syncthreads();

        // ---- per-thread c/h update (c stays in registers across all t) ----
        float hv[4];
#pragma unroll
        for (int j = 0; j < 4; ++j) {
            int c = ec4 + j;
            float gg = ftanh(Ex[0][erow][c] + biasS[0][c]);
            float ff = ftanh(Ex[1][erow][c] + biasS[1][c]);
            float ii = ftanh(Ex[2][erow][c] + biasS[2][c]);
            float oo = ftanh(Ex[3][erow][c] + biasS[3][c]);
            float cn = gg * ii + cst[j] * ff;
            cst[j] = cn;
            hv[j] = ftanh(cn) * oo;
        }
        union { _Float16 h4[4]; unsigned long long u; } pk;
#pragma unroll
        for (int j = 0; j < 4; ++j) pk.h4[j] = (_Float16)hv[j];
        *(unsigned long long*)(h_out + (size_t)(r0 + erow) * H_DIM + hc0 + ec4) = pk.u;
        if (t == T_LEN - 1) {
            floatx4 hvv = {hv[0], hv[1], hv[2], hv[3]};
            *(floatx4*)(hf32 + (size_t)(r0 + erow) * H_DIM + hc0 + ec4) = hvv;
        }

        // ---- grid barrier (skip after last step) ----
        if (t < T_LEN - 1) {
            __syncthreads();
            if (tid == 0) {
                __hip_atomic_fetch_add(bar, 1u, __ATOMIC_RELEASE, __HIP_MEMORY_SCOPE_AGENT);
                unsigned target = (unsigned)NBLK * (unsigned)(t + 1);
                while (__hip_atomic_load(bar, __ATOMIC_RELAXED, __HIP_MEMORY_SCOPE_AGENT) < target)
                    __builtin_amdgcn_s_sleep(2);
            }
            __syncthreads();
            __builtin_amdgcn_fence(__ATOMIC_ACQUIRE, "agent");
        }
    }
}

// ---------------------------------------------------------------------------
// logits[256][1024(pad)] = h @ W_ph + b_p
// ---------------------------------------------------------------------------
__global__ void k_logits(const float* __restrict__ h, const float* __restrict__ Wp,
                         const float* __restrict__ bp, float* __restrict__ logits) {
    __shared__ float hs[32][65];
    int r0 = blockIdx.y * 32;
    int c0 = blockIdx.x * 64;
    int tid = threadIdx.x;
    int wave = tid >> 6, tx = tid & 63;
    int col = c0 + tx;
    float s[8];
#pragma unroll
    for (int i = 0; i < 8; ++i) s[i] = 0.f;
    for (int kc = 0; kc < 16; ++kc) {
        int k0 = kc * 64;
#pragma unroll
        for (int i = 0; i < 8; ++i) {
            int idx = tid + i * 256;
            hs[idx >> 6][idx & 63] = h[(size_t)(r0 + (idx >> 6)) * H_DIM + k0 + (idx & 63)];
        }
        __syncthreads();
        if (col < NCLASS) {
            for (int kk = 0; kk < 64; ++kk) {
                float wv = Wp[(size_t)(k0 + kk) * NCLASS + col];
#pragma unroll
                for (int rr = 0; rr < 8; ++rr) s[rr] += hs[wave * 8 + rr][kk] * wv;
            }
        }
        __syncthreads();
    }
    if (col < NCLASS) {
#pragma unroll
        for (int rr = 0; rr < 8; ++rr)
            logits[(size_t)(r0 + wave * 8 + rr) * 1024 + col] = s[rr] + bp[col];
    }
}

// ---------------------------------------------------------------------------
__global__ void k_softmax(const float* __restrict__ logits, float* __restrict__ out) {
    __shared__ float red[256];
    int row = blockIdx.x, tid = threadIdx.x;
    float v[4];
    float mx = -1e30f;
#pragma unroll
    for (int i = 0; i < 4; ++i) {
        int c = tid + i * 256;
        float z = (c < NCLASS) ? logits[(size_t)row * 1024 + c] : -1e30f;
        v[i] = z;
        mx = fmaxf(mx, z);
    }
    red[tid] = mx; __syncthreads();
    for (int s = 128; s > 0; s >>= 1) {
        if (tid < s) red[tid] = fmaxf(red[tid], red[tid + s]);
        __syncthreads();
    }
    mx = red[0]; __syncthreads();
    float sum = 0.f;
#pragma unroll
    for (int i = 0; i < 4; ++i) {
        int c = tid + i * 256;
        v[i] = (c < NCLASS) ? __expf(v[i] - mx) : 0.f;
        sum += v[i];
    }
    red[tid] = sum; __syncthreads();
    for (int s = 128; s > 0; s >>= 1) {
        if (tid < s) red[tid] += red[tid + s];
        __syncthreads();
    }
    float inv = 1.f / red[0];
#pragma unroll
    for (int i = 0; i < 4; ++i) {
        int c = tid + i * 256;
        if (c < NCLASS) out[(size_t)row * NCLASS + c] = v[i] * inv;
    }
}

// ---------------------------------------------------------------------------
extern "C" void kernel_launch(void* const* d_in, const int* in_sizes, int n_in,
                              void* d_out, int out_size, void* d_ws, size_t ws_size,
                              hipStream_t stream) {
    const float* x   = (const float*)d_in[0];
    const float* Wfx = (const float*)d_in[1];
    const float* Wfh = (const float*)d_in[2];
    const float* Wgx = (const float*)d_in[3];
    const float* Wgh = (const float*)d_in[4];
    const float* Wix = (const float*)d_in[5];
    const float* Wih = (const float*)d_in[6];
    const float* Wox = (const float*)d_in[7];
    const float* Woh = (const float*)d_in[8];
    const float* Wph = (const float*)d_in[9];
    const float* bf  = (const float*)d_in[10];
    const float* bg  = (const float*)d_in[11];
    const float* bi  = (const float*)d_in[12];
    const float* bo  = (const float*)d_in[13];
    const float* bp  = (const float*)d_in[14];
    float* outp = (float*)d_out;

    char* ws = (char*)d_ws;
    _Float16* xT    = (_Float16*)(ws);                       // 134217728
    _Float16* WcatT = (_Float16*)(ws + 134217728);           // 12582912
    float*    bias  = (float*)   (ws + 146800640);           // 16384
    _Float16* hb0   = (_Float16*)(ws + 146817024);           // 524288
    _Float16* hb1   = (_Float16*)(ws + 147341312);           // 524288
    float*    hf32  = (float*)   (ws + 147865600);           // 1048576
    float*    logit = (float*)   (ws + 148914176);           // 1048576
    unsigned int* bar = (unsigned int*)(ws + 149962752);     // 4 (+pad)

    k_transpose_x<<<dim3(16, 16, 256), dim3(32, 8), 0, stream>>>(x, xT);
    k_build_wcat<<<dim3(32, 32, 8), dim3(32, 8), 0, stream>>>(
        Wgh, Wfh, Wih, Woh, Wgx, Wfx, Wix, Wox, WcatT);
    k_init<<<512, 256, 0, stream>>>((unsigned int*)hb0, bias, bar, bg, bf, bi, bo);

    void* args[] = {(void*)&xT, (void*)&WcatT, (void*)&bias, (void*)&hb0,
                    (void*)&hb1, (void*)&hf32, (void*)&bar};
    (void)hipLaunchCooperativeKernel((const void*)k_lstm, dim3(NBLK), dim3(256),
                                     args, 0, stream);

    k_logits<<<dim3(16, 8), 256, 0, stream>>>(hf32, Wph, bp, logit);
    k_softmax<<<256, 256, 0, stream>>>(logit, outp);
}